// Round 8
// baseline (1654.833 us; speedup 1.0000x reference)
//
#include <hip/hip_runtime.h>
#include <math.h>

namespace {

constexpr int NB  = 64;     // batch
constexpr int NL  = 196;    // L
constexpr int NE  = 2048;   // E
constexpr int ND  = 512;    // D
constexpr int NA  = 512;    // A
constexpr int NM  = 512;    // M
constexpr int NV  = 30000;  // vocab
constexpr int NT  = 21;     // T
constexpr int NML = 20;     // max_len
constexpr int NG  = 4 * ND;                 // 2048 (gates, col-interleaved j*4+g)
constexpr int KXG = NM + NE;                // 2560 (gates K: [emb | gctx])
constexpr int KSPL = 8, KSL = KXG / KSPL;   // 320 = 5 x 64
// fused h-GEMM (per step) N-space: [d (512) | gate (2048) | hWhh' (2048)]
constexpr int NDG = ND + NE + NG;           // 4608
constexpr int OFF_GATE = ND;                // 512
constexpr int OFF_HWHH = ND + NE;           // 2560

// ---- workspace layout (float elements) ----
constexpr size_t WS_MEAN = 0;                                  // [64][2048]
constexpr size_t WS_C0   = WS_MEAN + (size_t)NB * NE;
constexpr size_t WS_C1   = WS_C0   + (size_t)NB * ND;
constexpr size_t WS_D    = WS_C1   + (size_t)NB * ND;          // [64][512]
constexpr size_t WS_GATE = WS_D    + (size_t)NB * NA;          // [64][2048] sigmoid applied
constexpr size_t WS_HWHH = WS_GATE + (size_t)NB * NE;          // [64][2048] interleaved
constexpr size_t WS_EN   = WS_HWHH + (size_t)NB * NG;          // (unused)
constexpr size_t WS_PP   = WS_EN   + (size_t)NB * NL;          // 1048576 (init/gates partials)
constexpr size_t WS_SHB  = WS_PP   + (size_t)1048576;          // short region start
// (short elements from shb)
constexpr size_t SH_HALL = 0;                                  // [21][64][512] h_0..h_20
constexpr size_t SH_XEMB = SH_HALL + (size_t)(NML + 1) * NB * ND;  // [20][64][512]
constexpr size_t SH_GCTX = SH_XEMB + (size_t)NML * NB * NM;    // [64][2048]
constexpr size_t SH_EPROJ= SH_GCTX + (size_t)NB * NE;          // [12544][512]
constexpr size_t SH_WET  = SH_EPROJ+ (size_t)NB * NL * NA;     // [512][2048]
constexpr size_t SH_WIHX = SH_WET  + (size_t)NA * NE;          // [2048][2560] col-perm
constexpr size_t SH_WALL = SH_WIHX + (size_t)NG * KXG;         // [4608][512]
constexpr size_t SH_WFC  = SH_WALL + (size_t)NDG * ND;         // [30000][512]
constexpr size_t SH_ENCBF= SH_WFC  + (size_t)NV * ND;          // [64][196][2048] optional
constexpr size_t SH_END  = SH_ENCBF+ (size_t)NB * NL * NE;
constexpr size_t BYTES_ENC = WS_SHB * 4 + SH_END * 2;

typedef __attribute__((ext_vector_type(8))) short short8v;
typedef __attribute__((ext_vector_type(4))) float f32x4;

__device__ __forceinline__ float sigmoidf_(float x) { return 1.f / (1.f + expf(-x)); }
__device__ __forceinline__ short f2bf(float f) {
  unsigned u = __float_as_uint(f);
  return (short)((u + 0x7FFFu + ((u >> 16) & 1u)) >> 16);
}
__device__ __forceinline__ float bf2f(short s) {
  return __uint_as_float(((unsigned)(unsigned short)s) << 16);
}

// ---------- MFMA building blocks ----------
// LDS tile: [row][64 k] bf16, 8 x 16B chunks/row, chunk for global kb at slot
// kb ^ (row&7). Staged via global_load_lds with PRE-SWIZZLED global source.

__device__ __forceinline__ void gload16(const short* g, short* l) {
  __builtin_amdgcn_global_load_lds(
      (const __attribute__((address_space(1))) unsigned int*)(g),
      (__attribute__((address_space(3))) unsigned int*)(l), 16, 0, 0);
}

template <int R>  // stage R rows x 64 k bf16 (R multiple of 8); 4 waves
__device__ __forceinline__ void stage_direct(const short* __restrict__ src, int ldK,
                                             int rowClamp, short* lds, int tid) {
  int wv = tid >> 6, lane = tid & 63;
  int sub = lane >> 3;             // dest row within 8-row group
  int kb  = (lane & 7) ^ sub;      // pre-swizzled source chunk
#pragma unroll
  for (int g = wv; g < R / 8; g += 4) {
    int row = g * 8 + sub;
    int r = row < rowClamp ? row : rowClamp;
    gload16(src + (size_t)r * ldK + (kb << 3), lds + g * 512);
  }
}

template <int R>  // reg-staged f32->bf16 fallback (writes swizzled slots directly)
__device__ __forceinline__ void stage_f32cvt(const float* __restrict__ src, int ldK,
                                             short* lds, int tid) {
#pragma unroll
  for (int cidx = tid; cidx < R * 8; cidx += 256) {
    int row = cidx >> 3, kb = cidx & 7;
    const float* p = src + (size_t)row * ldK + kb * 8;
    float4 x = *(const float4*)p;
    float4 y = *(const float4*)(p + 4);
    short8v s;
    s[0] = f2bf(x.x); s[1] = f2bf(x.y); s[2] = f2bf(x.z); s[3] = f2bf(x.w);
    s[4] = f2bf(y.x); s[5] = f2bf(y.y); s[6] = f2bf(y.z); s[7] = f2bf(y.w);
    *(short8v*)(lds + row * 64 + ((kb ^ (row & 7)) << 3)) = s;
  }
}

template <int FM, int FN>
__device__ __forceinline__ void mma_tiles(const short* ldsA, const short* ldsB,
                                          int wr, int wc, int lane, f32x4 acc[FM][FN]) {
  int l15 = lane & 15;
#pragma unroll
  for (int kk = 0; kk < 2; ++kk) {
    int kb0 = kk * 4 + (lane >> 4);
    short8v a[FM], b[FN];
#pragma unroll
    for (int m = 0; m < FM; ++m) {
      int row = wr * FM * 16 + m * 16 + l15;
      a[m] = *(const short8v*)(ldsA + row * 64 + ((kb0 ^ (row & 7)) << 3));
    }
#pragma unroll
    for (int n = 0; n < FN; ++n) {
      int row = wc * FN * 16 + n * 16 + l15;
      b[n] = *(const short8v*)(ldsB + row * 64 + ((kb0 ^ (row & 7)) << 3));
    }
#pragma unroll
    for (int m = 0; m < FM; ++m)
#pragma unroll
      for (int n = 0; n < FN; ++n)
        acc[m][n] = __builtin_amdgcn_mfma_f32_16x16x32_bf16(a[m], b[n], acc[m][n], 0, 0, 0);
  }
}

// ---------- one-time kernels ----------

// transpose+convert; PERM interleaves gate columns: n' = (n&511)*4 + (n>>9)
template <bool PERM>
__global__ __launch_bounds__(256) void k_tcvt(const float* __restrict__ src, int Ks, int Ns,
                                              short* __restrict__ dst, int ldDst, int kOff) {
  __shared__ float tbuf[32][33];
  int n0 = blockIdx.x * 32, k0 = blockIdx.y * 32;
  int tx = threadIdx.x, ty = threadIdx.y;  // 32 x 8
#pragma unroll
  for (int i = 0; i < 32; i += 8) {
    int k = k0 + ty + i, n = n0 + tx;
    tbuf[ty + i][tx] = (k < Ks && n < Ns) ? src[(size_t)k * Ns + n] : 0.f;
  }
  __syncthreads();
#pragma unroll
  for (int i = 0; i < 32; i += 8) {
    int n = n0 + ty + i, k = k0 + tx;
    if (n < Ns && k < Ks) {
      int nd = PERM ? (((n & 511) << 2) | (n >> 9)) : n;
      dst[(size_t)nd * ldDst + kOff + k] = f2bf(tbuf[tx][ty + i]);
    }
  }
}

// fused: encbf (optional) + column mean, single pass over enc. grid (8, 64)
template <bool BF>
__global__ __launch_bounds__(256) void k_prep(const float* __restrict__ enc,
                                              short* __restrict__ encbf,
                                              float* __restrict__ mean_enc) {
  int b = blockIdx.y;
  int e = blockIdx.x * 256 + threadIdx.x;
  const float* p = enc + (size_t)b * NL * NE + e;
  short* q = encbf + (size_t)b * NL * NE + e;
  float s = 0.f;
  for (int l = 0; l < NL; ++l) {
    float v = p[(size_t)l * NE];
    s += v;
    if (BF) q[(size_t)l * NE] = f2bf(v);
  }
  mean_enc[(size_t)b * NE + e] = s * (1.f / NL);
}

__global__ void k_xemb(const int* __restrict__ caps, const float* __restrict__ emb,
                       short* __restrict__ xemb) {
  int i = blockIdx.x * 256 + threadIdx.x;
  int m = i & (NM - 1), b = (i >> 9) & (NB - 1), t = i >> 15;
  xemb[i] = f2bf(emb[(size_t)caps[b * NT + t] * NM + m]);
}

// h0/c0 partials: 16-way K-split. grid (256, 16)
__global__ void k_init0(const float* __restrict__ mean_enc, const float* __restrict__ W_h0,
                        const float* __restrict__ W_c0, float* __restrict__ PP) {
  int idx = blockIdx.x * 256 + threadIdx.x;  // b*1024 + half*512 + j
  int ks = blockIdx.y;
  int b = idx >> 10, jh = idx & 1023, half = jh >> 9, j = jh & 511;
  const float* W = half ? W_c0 : W_h0;
  const float* mp = mean_enc + (size_t)b * NE + ks * 128;
  const float* Wp = W + (size_t)(ks * 128) * ND + j;
  float acc = 0.f;
#pragma unroll 4
  for (int k = 0; k < 128; ++k) acc = fmaf(mp[k], Wp[(size_t)k * ND], acc);
  PP[(size_t)ks * 65536 + idx] = acc;
}

__global__ void k_init1(const float* __restrict__ PP, const float* __restrict__ b_h0,
                        const float* __restrict__ b_c0, float* __restrict__ c0,
                        short* __restrict__ h0) {
  int idx = blockIdx.x * 256 + threadIdx.x;  // b*512 + j
  int b = idx >> 9, j = idx & 511;
  float ah = b_h0[j], ac = b_c0[j];
  for (int s = 0; s < 16; ++s) {
    const float* p = PP + (size_t)s * 65536 + b * 1024;
    ah += p[j]; ac += p[512 + j];
  }
  c0[idx] = tanhf(ac);
  h0[idx] = f2bf(tanhf(ah));
}

// e_proj = enc @ W_enc + b_enc (bf16 out). 128x128 tile, 1D grid 392, XCD-chunked
template <bool BF>
__global__ __launch_bounds__(256) void k_eproj(const float* __restrict__ enc,
                                               const short* __restrict__ encbf,
                                               const short* __restrict__ We_t,
                                               const float* __restrict__ b_enc,
                                               short* __restrict__ e_proj) {
  constexpr int FM = 4, FN = 4;  // 128 x 128
  __shared__ short ldsA[128 * 64], ldsB[128 * 64];
  int p = blockIdx.x;
  int l = (p & 7) * 49 + (p >> 3);       // 392 = 8*49, contiguous per XCD
  int bn = (l & 3) * 128, bm = (l >> 2) * 128;
  int tid = threadIdx.x, lane = tid & 63, wave = tid >> 6, wr = wave >> 1, wc = wave & 1;
  f32x4 acc[FM][FN];
#pragma unroll
  for (int m = 0; m < FM; ++m)
#pragma unroll
    for (int n = 0; n < FN; ++n) acc[m][n] = (f32x4){0.f, 0.f, 0.f, 0.f};
  for (int k0 = 0; k0 < NE; k0 += 64) {
    __syncthreads();
    if (BF) stage_direct<128>(encbf + (size_t)bm * NE + k0, NE, 127, ldsA, tid);
    else    stage_f32cvt<128>(enc + (size_t)bm * NE + k0, NE, ldsA, tid);
    stage_direct<128>(We_t + (size_t)bn * NE + k0, NE, 127, ldsB, tid);
    __syncthreads();
    mma_tiles<FM, FN>(ldsA, ldsB, wr, wc, lane, acc);
  }
#pragma unroll
  for (int m = 0; m < FM; ++m)
#pragma unroll
    for (int n = 0; n < FN; ++n) {
      int col = bn + wc * FN * 16 + n * 16 + (lane & 15);
      float bias = b_enc[col];
#pragma unroll
      for (int r = 0; r < 4; ++r) {
        int row = bm + wr * FM * 16 + m * 16 + (lane >> 4) * 4 + r;
        e_proj[(size_t)row * NA + col] = f2bf(acc[m][n][r] + bias);
      }
    }
}

// per-step h-GEMM: h [64,512] @ Wall_t^T -> d | gate | hWhh'. 64x64 tile, 72 blocks
__global__ __launch_bounds__(256) void k_hgemm_dg(const short* __restrict__ h_bf,
                                                  const short* __restrict__ Wall_t,
                                                  const float* __restrict__ b_dec,
                                                  const float* __restrict__ b_beta,
                                                  float* __restrict__ d_buf,
                                                  float* __restrict__ gatebuf,
                                                  float* __restrict__ hWhh) {
  constexpr int FM = 2, FN = 2;  // 64 x 64, 4 waves
  __shared__ short ldsA[64 * 64], ldsB[64 * 64];
  int bn = blockIdx.x * 64;
  int tid = threadIdx.x, lane = tid & 63, wave = tid >> 6, wr = wave >> 1, wc = wave & 1;
  f32x4 acc[FM][FN];
#pragma unroll
  for (int m = 0; m < FM; ++m)
#pragma unroll
    for (int n = 0; n < FN; ++n) acc[m][n] = (f32x4){0.f, 0.f, 0.f, 0.f};
  for (int k0 = 0; k0 < ND; k0 += 64) {
    __syncthreads();
    stage_direct<64>(h_bf + k0, ND, 63, ldsA, tid);
    stage_direct<64>(Wall_t + (size_t)bn * ND + k0, ND, 63, ldsB, tid);
    __syncthreads();
    mma_tiles<FM, FN>(ldsA, ldsB, wr, wc, lane, acc);
  }
#pragma unroll
  for (int m = 0; m < FM; ++m)
#pragma unroll
    for (int r = 0; r < 4; ++r) {
      int row = wr * FM * 16 + m * 16 + (lane >> 4) * 4 + r;  // batch
#pragma unroll
      for (int n = 0; n < FN; ++n) {
        int col = bn + wc * FN * 16 + n * 16 + (lane & 15);
        float a = acc[m][n][r];
        if (bn < OFF_GATE) {
          d_buf[(size_t)row * NA + col] = a + b_dec[col];
        } else if (bn < OFF_HWHH) {
          int e = col - OFF_GATE;
          gatebuf[(size_t)row * NE + e] = sigmoidf_(a + b_beta[e]);
        } else {
          hWhh[(size_t)row * NG + (col - OFF_HWHH)] = a;
        }
      }
    }
}

// ---------- per-step kernels ----------

// fused attention: energy (in-block recompute) + softmax + ctx + gate -> gctx.
// grid (4, 64), 256 thr. Energy arithmetic identical to old k_energy.
template <bool BF>
__global__ __launch_bounds__(256) void k_actx(const short* __restrict__ e_proj,
                                              const float* __restrict__ d_buf,
                                              const float* __restrict__ w_att,
                                              const float* __restrict__ b_att,
                                              const short* __restrict__ encbf,
                                              const float* __restrict__ encf,
                                              const float* __restrict__ gatebuf,
                                              const int* __restrict__ clen,
                                              short* __restrict__ gctx,
                                              float* __restrict__ alphas_out, int t) {
  int b = blockIdx.y, e0 = blockIdx.x * 512, tid = threadIdx.x;
  __shared__ float e_sh[NL];
  __shared__ float al[NL];
  __shared__ float red[8];
  int wave = tid >> 6, lane = tid & 63;
  // per-lane d / w_att registers (a = lane*8 + i), invariant across rows
  const float* dp = d_buf + (size_t)b * NA + lane * 8;
  float4 d0v = *(const float4*)dp, d1v = *(const float4*)(dp + 4);
  const float* wp = w_att + lane * 8;
  float4 w0v = *(const float4*)wp, w1v = *(const float4*)(wp + 4);
  float dd[8] = {d0v.x, d0v.y, d0v.z, d0v.w, d1v.x, d1v.y, d1v.z, d1v.w};
  float ww[8] = {w0v.x, w0v.y, w0v.z, w0v.w, w1v.x, w1v.y, w1v.z, w1v.w};
  float batt = b_att[0];
  for (int l = wave; l < NL; l += 4) {
    short8v ev = *(const short8v*)(e_proj + (size_t)(b * NL + l) * NA + lane * 8);
    float acc = 0.f;
#pragma unroll
    for (int i = 0; i < 8; ++i) {
      float v = bf2f(ev[i]) + dd[i];
      acc = fmaf(fmaxf(v, 0.f), ww[i], acc);
    }
#pragma unroll
    for (int off = 32; off; off >>= 1) acc += __shfl_down(acc, off);
    if (lane == 0) e_sh[l] = acc + batt;
  }
  __syncthreads();
  float v = (tid < NL) ? e_sh[tid] : -INFINITY;
  float mx = v;
#pragma unroll
  for (int off = 32; off; off >>= 1) mx = fmaxf(mx, __shfl_down(mx, off));
  if (lane == 0) red[wave] = mx;
  __syncthreads();
  if (tid == 0) red[0] = fmaxf(fmaxf(red[0], red[1]), fmaxf(red[2], red[3]));
  __syncthreads();
  mx = red[0];
  float ex = (tid < NL) ? expf(v - mx) : 0.f;
  float sm = ex;
#pragma unroll
  for (int off = 32; off; off >>= 1) sm += __shfl_down(sm, off);
  if (lane == 0) red[4 + wave] = sm;
  __syncthreads();
  if (tid == 0) red[0] = 1.f / (red[4] + red[5] + red[6] + red[7]);
  __syncthreads();
  float alv = ex * red[0];
  if (tid < NL) {
    al[tid] = alv;
    if (blockIdx.x == 0) {
      float mf = ((clen[b] - 1) > t) ? 1.f : 0.f;
      alphas_out[((size_t)b * NML + t) * NL + tid] = alv * mf;
    }
  }
  __syncthreads();
  float cx0 = 0.f, cx1 = 0.f;
  if (BF) {
    const unsigned* p = (const unsigned*)(encbf + (size_t)b * NL * NE + e0) + tid;
#pragma unroll 4
    for (int l = 0; l < NL; ++l) {
      unsigned u = p[(size_t)l * (NE / 2)];
      cx0 = fmaf(al[l], bf2f((short)(u & 0xffffu)), cx0);
      cx1 = fmaf(al[l], bf2f((short)(u >> 16)), cx1);
    }
  } else {
    const float* p = encf + (size_t)b * NL * NE + e0 + 2 * tid;
#pragma unroll 4
    for (int l = 0; l < NL; ++l) {
      float2 u = *(const float2*)(p + (size_t)l * NE);
      cx0 = fmaf(al[l], u.x, cx0);
      cx1 = fmaf(al[l], u.y, cx1);
    }
  }
  int e = e0 + 2 * tid;
  const float* gp = gatebuf + (size_t)b * NE + e;
  unsigned out = (unsigned)(unsigned short)f2bf(cx0 * gp[0]) |
                 ((unsigned)(unsigned short)f2bf(cx1 * gp[1]) << 16);
  *(unsigned*)(gctx + (size_t)b * NE + e) = out;
}

// gates GEMM [emb|gctx] @ Wihx_t^T (col-interleaved) -> P[ks][64][2048]. grid (32, 8)
__global__ __launch_bounds__(256) void k_gates(const short* __restrict__ xemb_t,
                                               const short* __restrict__ gctx,
                                               const short* __restrict__ Wihx_t,
                                               float* __restrict__ P) {
  constexpr int FM = 2, FN = 2;  // 64 x 64
  __shared__ short ldsA[64 * 64], ldsB[64 * 64];
  int bn = blockIdx.x * 64, ks = blockIdx.y;
  int tid = threadIdx.x, lane = tid & 63, wave = tid >> 6, wr = wave >> 1, wc = wave & 1;
  f32x4 acc[FM][FN];
#pragma unroll
  for (int m = 0; m < FM; ++m)
#pragma unroll
    for (int n = 0; n < FN; ++n) acc[m][n] = (f32x4){0.f, 0.f, 0.f, 0.f};
  int kend = (ks + 1) * KSL;
  for (int k0 = ks * KSL; k0 < kend; k0 += 64) {
    const short* asrc; int aldk;
    if (k0 < NM) { asrc = xemb_t + k0;      aldk = NM; }
    else         { asrc = gctx + (k0 - NM); aldk = NE; }
    __syncthreads();
    stage_direct<64>(asrc, aldk, 63, ldsA, tid);
    stage_direct<64>(Wihx_t + (size_t)bn * KXG + k0, KXG, 63, ldsB, tid);
    __syncthreads();
    mma_tiles<FM, FN>(ldsA, ldsB, wr, wc, lane, acc);
  }
#pragma unroll
  for (int m = 0; m < FM; ++m)
#pragma unroll
    for (int n = 0; n < FN; ++n) {
      int col = bn + wc * FN * 16 + n * 16 + (lane & 15);
#pragma unroll
      for (int r = 0; r < 4; ++r) {
        int row = wr * FM * 16 + m * 16 + (lane >> 4) * 4 + r;
        P[((size_t)ks * NB + row) * NG + col] = acc[m][n][r];
      }
    }
}

// reduce partials + hWhh' (col-interleaved float4 = {i,f,g,o}), LSTM pointwise
__global__ void k_lstm(const float* __restrict__ P, const float* __restrict__ hWhh,
                       const float* __restrict__ b_ih, const float* __restrict__ b_hh,
                       const float* __restrict__ c_prev, float* __restrict__ c_next,
                       short* __restrict__ h_next) {
  int idx = blockIdx.x * 256 + threadIdx.x;  // b*512 + j
  int b = idx >> 9, j = idx & (ND - 1);
  float4 hw = *(const float4*)&hWhh[(size_t)b * NG + j * 4];
  float gi = b_ih[j] + b_hh[j] + hw.x;
  float gf = b_ih[j + ND] + b_hh[j + ND] + hw.y;
  float gg = b_ih[j + 2 * ND] + b_hh[j + 2 * ND] + hw.z;
  float go = b_ih[j + 3 * ND] + b_hh[j + 3 * ND] + hw.w;
#pragma unroll
  for (int s = 0; s < KSPL; ++s) {
    float4 v = *(const float4*)&P[((size_t)s * NB + b) * NG + j * 4];
    gi += v.x; gf += v.y; gg += v.z; go += v.w;
  }
  float cn = sigmoidf_(gf) * c_prev[idx] + sigmoidf_(gi) * tanhf(gg);
  float hn = sigmoidf_(go) * tanhf(cn);
  c_next[idx] = cn;
  h_next[idx] = f2bf(hn);
}

// ---------- epilogue: batched pred GEMM ----------
// preds[b][t][v] = mask * (h_{t+1} . Wfc[:,v] + b_fc[v]);  A rows = t*64 + b
// M = 1280, N = 30000, K = 512. 128x128 tiles, grid 2350, XCD-bijective n-major.
// Epilogue: acc -> LDS (stride-129 f32) -> coalesced float4 row-segment stores.
__global__ __launch_bounds__(256) void k_pred(const short* __restrict__ h_all1,
                                              const short* __restrict__ Wfc_t,
                                              const float* __restrict__ b_fc,
                                              const int* __restrict__ clen,
                                              float* __restrict__ preds) {
  constexpr int FM = 4, FN = 4;  // 128 x 128
  constexpr int NT_M = 10, NT_N = (NV + 127) / 128;  // 10 x 235 = 2350
  constexpr int TOT = NT_M * NT_N;
  __shared__ __align__(16) char smem[64 * 129 * 4];  // 33024 B >= 2*16KB staging
  short* ldsA = (short*)smem;
  short* ldsB = ldsA + 128 * 64;
  float* fl   = (float*)smem;                         // [64][129] f32 view
  int p = blockIdx.x;
  int q = TOT / 8, r8 = TOT % 8;
  int xcd = p & 7, i = p >> 3;
  int l = (xcd < r8 ? xcd * (q + 1) : r8 * (q + 1) + (xcd - r8) * q) + i;
  int bm = (l % NT_M) * 128, bn = (l / NT_M) * 128;
  int tid = threadIdx.x, lane = tid & 63, wave = tid >> 6, wr = wave >> 1, wc = wave & 1;
  int rowClampB = NV - 1 - bn; if (rowClampB > 127) rowClampB = 127;
  f32x4 acc[FM][FN];
#pragma unroll
  for (int m = 0; m < FM; ++m)
#pragma unroll
    for (int n = 0; n < FN; ++n) acc[m][n] = (f32x4){0.f, 0.f, 0.f, 0.f};
  for (int k0 = 0; k0 < ND; k0 += 64) {
    __syncthreads();
    stage_direct<128>(h_all1 + (size_t)bm * ND + k0, ND, 127, ldsA, tid);
    stage_direct<128>(Wfc_t + (size_t)bn * ND + k0, ND, rowClampB, ldsB, tid);
    __syncthreads();
    mma_tiles<FM, FN>(ldsA, ldsB, wr, wc, lane, acc);
  }
  __syncthreads();  // staging reads done; reuse LDS for transpose-store
#pragma unroll
  for (int h = 0; h < 2; ++h) {
    if (wr == h) {
#pragma unroll
      for (int m = 0; m < FM; ++m)
#pragma unroll
        for (int n = 0; n < FN; ++n)
#pragma unroll
          for (int r = 0; r < 4; ++r) {
            int lr = m * 16 + (lane >> 4) * 4 + r;      // 0..63
            int lc = wc * 64 + n * 16 + (lane & 15);    // 0..127
            fl[lr * 129 + lc] = acc[m][n][r];
          }
    }
    __syncthreads();
    {
      int lr = tid & 63, cs = (tid >> 6) * 32;
      int grow = bm + h * 64 + lr;
      int tt = grow >> 6, bb = grow & 63;
      float mf = ((clen[bb] - 1) > tt) ? 1.f : 0.f;
      size_t obase = ((size_t)bb * NML + tt) * NV + bn + cs;
#pragma unroll
      for (int j = 0; j < 8; ++j) {
        int col = bn + cs + j * 4;
        if (col < NV) {
          const float* fp = &fl[lr * 129 + cs + j * 4];
          float4 v;
          v.x = mf * (fp[0] + b_fc[col]);
          v.y = mf * (fp[1] + b_fc[col + 1]);
          v.z = mf * (fp[2] + b_fc[col + 2]);
          v.w = mf * (fp[3] + b_fc[col + 3]);
          *(float4*)(preds + obase + j * 4) = v;
        }
      }
    }
    __syncthreads();
  }
}

}  // namespace

extern "C" void kernel_launch(void* const* d_in, const int* in_sizes, int n_in,
                              void* d_out, int out_size, void* d_ws, size_t ws_size,
                              hipStream_t stream) {
  (void)in_sizes; (void)n_in; (void)out_size;
  const float* enc    = (const float*)d_in[0];
  const int*   caps   = (const int*)d_in[1];
  const int*   clen   = (const int*)d_in[2];
  const float* W_enc  = (const float*)d_in[3];
  const float* b_enc  = (const float*)d_in[4];
  const float* W_dec  = (const float*)d_in[5];
  const float* b_dec  = (const float*)d_in[6];
  const float* w_att  = (const float*)d_in[7];
  const float* b_att  = (const float*)d_in[8];
  const float* emb    = (const float*)d_in[9];
  const float* W_ih   = (const float*)d_in[10];
  const float* b_ih   = (const float*)d_in[11];
  const float* W_hh   = (const float*)d_in[12];
  const float* b_hh   = (const float*)d_in[13];
  const float* W_h0   = (const float*)d_in[14];
  const float* b_h0   = (const float*)d_in[15];
  const float* W_c0   = (const float*)d_in[16];
  const float* b_c0   = (const float*)d_in[17];
  const float* W_beta = (const float*)d_in[18];
  const float* b_beta = (const float*)d_in[19];
  const float* W_fc   = (const float*)d_in[20];
  const float* b_fc   = (const float*)d_in[21];

  float* ws     = (float*)d_ws;
  float* preds  = (float*)d_out;                   // [B][ML][V]
  float* alphas = preds + (size_t)NB * NML * NV;   // [B][ML][L]

  float* mean_enc = ws + WS_MEAN;
  float* cbuf[2]  = {ws + WS_C0, ws + WS_C1};
  float* d_buf    = ws + WS_D;
  float* gatebuf  = ws + WS_GATE;
  float* hWhh     = ws + WS_HWHH;
  float* PP       = ws + WS_PP;
  short* shb      = (short*)(ws + WS_SHB);
  short* h_all    = shb + SH_HALL;                 // [21][64][512]
  short* xemb     = shb + SH_XEMB;
  short* gctx     = shb + SH_GCTX;
  short* e_proj   = shb + SH_EPROJ;
  short* We_t     = shb + SH_WET;
  short* Wihx_t   = shb + SH_WIHX;
  short* Wall_t   = shb + SH_WALL;
  short* Wfc_t    = shb + SH_WFC;
  short* encbf    = shb + SH_ENCBF;
  const bool use_bf = ws_size >= BYTES_ENC;

  // one-time weight transposes (dst[n][k] bf16)
  k_tcvt<false><<<dim3(NA / 32, NE / 32), dim3(32, 8), 0, stream>>>(W_enc, NE, NA, We_t, NE, 0);
  k_tcvt<true><<<dim3(NG / 32, KXG / 32), dim3(32, 8), 0, stream>>>(
      W_ih, KXG, NG, Wihx_t, KXG, 0);
  k_tcvt<false><<<dim3(NA / 32, ND / 32), dim3(32, 8), 0, stream>>>(W_dec, ND, NA, Wall_t, ND, 0);
  k_tcvt<false><<<dim3(NE / 32, ND / 32), dim3(32, 8), 0, stream>>>(
      W_beta, ND, NE, Wall_t + (size_t)OFF_GATE * ND, ND, 0);
  k_tcvt<true><<<dim3(NG / 32, ND / 32), dim3(32, 8), 0, stream>>>(
      W_hh, ND, NG, Wall_t + (size_t)OFF_HWHH * ND, ND, 0);
  k_tcvt<false><<<dim3((NV + 31) / 32, ND / 32), dim3(32, 8), 0, stream>>>(
      W_fc, ND, NV, Wfc_t, ND, 0);
  if (use_bf)
    k_prep<true><<<dim3(NE / 256, NB), 256, 0, stream>>>(enc, encbf, mean_enc);
  else
    k_prep<false><<<dim3(NE / 256, NB), 256, 0, stream>>>(enc, encbf, mean_enc);
  k_xemb<<<(NML * NB * NM) / 256, 256, 0, stream>>>(caps, emb, xemb);

  k_init0<<<dim3(256, 16), 256, 0, stream>>>(mean_enc, W_h0, W_c0, PP);
  k_init1<<<(NB * ND) / 256, 256, 0, stream>>>(PP, b_h0, b_c0, cbuf[0], h_all);
  if (use_bf)
    k_eproj<true><<<392, 256, 0, stream>>>(enc, encbf, We_t, b_enc, e_proj);
  else
    k_eproj<false><<<392, 256, 0, stream>>>(enc, encbf, We_t, b_enc, e_proj);
  // h0-dependent d / gate / hWhh'
  k_hgemm_dg<<<NDG / 64, 256, 0, stream>>>(h_all, Wall_t, b_dec, b_beta,
                                           d_buf, gatebuf, hWhh);

  for (int t = 0; t < NML; ++t) {
    short* h_next = h_all + (size_t)(t + 1) * NB * ND;
    float* c_prev = cbuf[t & 1];
    float* c_next = cbuf[1 - (t & 1)];
    if (use_bf)
      k_actx<true><<<dim3(NE / 512, NB), 256, 0, stream>>>(e_proj, d_buf, w_att, b_att,
                                                           encbf, enc, gatebuf, clen,
                                                           gctx, alphas, t);
    else
      k_actx<false><<<dim3(NE / 512, NB), 256, 0, stream>>>(e_proj, d_buf, w_att, b_att,
                                                            encbf, enc, gatebuf, clen,
                                                            gctx, alphas, t);
    k_gates<<<dim3(NG / 64, KSPL), 256, 0, stream>>>(xemb + (size_t)t * NB * NM, gctx,
                                                     Wihx_t, PP);
    k_lstm<<<(NB * ND) / 256, 256, 0, stream>>>(PP, hWhh, b_ih, b_hh, c_prev, c_next,
                                                h_next);
    if (t + 1 < NML)  // d / gate / hWhh' for step t+1
      k_hgemm_dg<<<NDG / 64, 256, 0, stream>>>(h_next, Wall_t, b_dec, b_beta,
                                               d_buf, gatebuf, hWhh);
  }
  // batched pred GEMM: all 20 steps at once, W_fc read once
  k_pred<<<10 * ((NV + 127) / 128), 256, 0, stream>>>(h_all + (size_t)NB * ND, Wfc_t,
                                                      b_fc, clen, preds);
}

// Round 10
// 1157.584 us; speedup vs baseline: 1.4296x; 1.4296x over previous
//
#include <hip/hip_runtime.h>
#include <math.h>

namespace {

constexpr int NB  = 64;     // batch
constexpr int NL  = 196;    // L
constexpr int NE  = 2048;   // E
constexpr int ND  = 512;    // D
constexpr int NA  = 512;    // A
constexpr int NM  = 512;    // M
constexpr int NV  = 30000;  // vocab
constexpr int NT  = 21;     // T
constexpr int NML = 20;     // max_len
constexpr int NG  = 4 * ND;                 // 2048 (gates, col-interleaved j*4+g)
constexpr int KXG = NM + NE;                // 2560 (gates K: [emb | gctx])
constexpr int KSPL = 8, KSL = KXG / KSPL;   // 320
// fused h-GEMM N-space: [d (512) | gate (2048) | pred (30000)]
constexpr int NALL = ND + NE + NV;          // 32560
constexpr int OFF_GATE = ND;                // 512
constexpr int OFF_PRED = ND + NE;           // 2560
// note: hWhh handled via gates? no — this config keeps hWhh in gates-K? No:
// this is the round-6 config: gates K = [emb|gctx] (2560), hWhh inside k_hgemm
// N-space. Wait — round-6 k_hgemm N-space was [d|gate|pred] with hWhh folded
// into k_gates' K=3072? No. Round-6: k_hgemm = d|gate|pred (NALL=32560) and
// hWhh came from... k_gates K=2560 [emb|gctx] + k_lstm reads hWhh... 
// CORRECT round-6 layout: k_hgemm emits d|gate|preds; W_hh contribution is a
// separate region? It was in k_gates? — No: round-6 k_lstm reads hWhh from
// k_hgemm's OFF_HWHH region. Restored faithfully below via NALL2 layout.

constexpr int OFF_HWHH2 = ND + NE;          // 2560 (hWhh region start)
constexpr int OFF_PRED2 = ND + NE + NG;     // 4608 (pred region start)
constexpr int NALL2 = ND + NE + NG + NV;    // 34608 total h-GEMM columns

// ---- workspace layout (float elements) ----
constexpr size_t WS_MEAN = 0;                                  // [64][2048]
constexpr size_t WS_C0   = WS_MEAN + (size_t)NB * NE;
constexpr size_t WS_C1   = WS_C0   + (size_t)NB * ND;
constexpr size_t WS_D    = WS_C1   + (size_t)NB * ND;          // [64][512]
constexpr size_t WS_GATE = WS_D    + (size_t)NB * NA;          // [64][2048]
constexpr size_t WS_HWHH = WS_GATE + (size_t)NB * NE;          // [64][2048] interleaved
constexpr size_t WS_EN   = WS_HWHH + (size_t)NB * NG;          // [64][196]
constexpr size_t WS_PP   = WS_EN   + (size_t)NB * NL;          // 1048576
constexpr size_t WS_SHB  = WS_PP   + (size_t)1048576;
// (short elements from shb)
constexpr size_t SH_HB0  = 0;                                  // [64][512]
constexpr size_t SH_HB1  = SH_HB0  + (size_t)NB * ND;
constexpr size_t SH_XEMB = SH_HB1  + (size_t)NB * ND;          // [20][64][512]
constexpr size_t SH_GCTX = SH_XEMB + (size_t)NML * NB * NM;    // [64][2048]
constexpr size_t SH_EPROJ= SH_GCTX + (size_t)NB * NE;          // [12544][512]
constexpr size_t SH_WET  = SH_EPROJ+ (size_t)NB * NL * NA;     // [512][2048]
constexpr size_t SH_WIHX = SH_WET  + (size_t)NA * NE;          // [2048][2560]
constexpr size_t SH_WALL = SH_WIHX + (size_t)NG * KXG;         // [34608][512]
constexpr size_t SH_ENCBF= SH_WALL + (size_t)NALL2 * ND;       // [64][196][2048] optional
constexpr size_t SH_END  = SH_ENCBF+ (size_t)NB * NL * NE;
constexpr size_t BYTES_ENC = WS_SHB * 4 + SH_END * 2;

typedef __attribute__((ext_vector_type(8))) short short8v;
typedef __attribute__((ext_vector_type(4))) float f32x4;

__device__ __forceinline__ float sigmoidf_(float x) { return 1.f / (1.f + expf(-x)); }
__device__ __forceinline__ short f2bf(float f) {
  unsigned u = __float_as_uint(f);
  return (short)((u + 0x7FFFu + ((u >> 16) & 1u)) >> 16);
}
__device__ __forceinline__ float bf2f(short s) {
  return __uint_as_float(((unsigned)(unsigned short)s) << 16);
}

// ---------- MFMA building blocks ----------
// LDS tile: [row][64 k] bf16, 8 x 16B chunks/row, chunk for global kb at slot
// kb ^ (row&7). Staged via global_load_lds with PRE-SWIZZLED global source
// (linear LDS dest = wave-uniform base + lane*16B).

__device__ __forceinline__ void gload16(const short* g, short* l) {
  __builtin_amdgcn_global_load_lds(
      (const __attribute__((address_space(1))) unsigned int*)(g),
      (__attribute__((address_space(3))) unsigned int*)(l), 16, 0, 0);
}

template <int R>  // stage R rows x 64 k bf16 (R multiple of 8); 4 waves
__device__ __forceinline__ void stage_direct(const short* __restrict__ src, int ldK,
                                             int rowClamp, short* lds, int tid) {
  int wv = tid >> 6, lane = tid & 63;
  int sub = lane >> 3;
  int kb  = (lane & 7) ^ sub;
#pragma unroll
  for (int g = wv; g < R / 8; g += 4) {
    int row = g * 8 + sub;
    int r = row < rowClamp ? row : rowClamp;
    gload16(src + (size_t)r * ldK + (kb << 3), lds + g * 512);
  }
}

template <int R>  // reg-staged f32->bf16 fallback (writes swizzled slots directly)
__device__ __forceinline__ void stage_f32cvt(const float* __restrict__ src, int ldK,
                                             short* lds, int tid) {
#pragma unroll
  for (int cidx = tid; cidx < R * 8; cidx += 256) {
    int row = cidx >> 3, kb = cidx & 7;
    const float* p = src + (size_t)row * ldK + kb * 8;
    float4 x = *(const float4*)p;
    float4 y = *(const float4*)(p + 4);
    short8v s;
    s[0] = f2bf(x.x); s[1] = f2bf(x.y); s[2] = f2bf(x.z); s[3] = f2bf(x.w);
    s[4] = f2bf(y.x); s[5] = f2bf(y.y); s[6] = f2bf(y.z); s[7] = f2bf(y.w);
    *(short8v*)(lds + row * 64 + ((kb ^ (row & 7)) << 3)) = s;
  }
}

template <int FM, int FN>
__device__ __forceinline__ void mma_tiles(const short* ldsA, const short* ldsB,
                                          int wr, int wc, int lane, f32x4 acc[FM][FN]) {
  int l15 = lane & 15;
#pragma unroll
  for (int kk = 0; kk < 2; ++kk) {
    int kb0 = kk * 4 + (lane >> 4);
    short8v a[FM], b[FN];
#pragma unroll
    for (int m = 0; m < FM; ++m) {
      int row = wr * FM * 16 + m * 16 + l15;
      a[m] = *(const short8v*)(ldsA + row * 64 + ((kb0 ^ (row & 7)) << 3));
    }
#pragma unroll
    for (int n = 0; n < FN; ++n) {
      int row = wc * FN * 16 + n * 16 + l15;
      b[n] = *(const short8v*)(ldsB + row * 64 + ((kb0 ^ (row & 7)) << 3));
    }
#pragma unroll
    for (int m = 0; m < FM; ++m)
#pragma unroll
      for (int n = 0; n < FN; ++n)
        acc[m][n] = __builtin_amdgcn_mfma_f32_16x16x32_bf16(a[m], b[n], acc[m][n], 0, 0, 0);
  }
}

// ---------- one-time kernels ----------

// transpose+convert; PERM interleaves gate columns: n' = (n&511)*4 + (n>>9)
template <bool PERM>
__global__ __launch_bounds__(256) void k_tcvt(const float* __restrict__ src, int Ks, int Ns,
                                              short* __restrict__ dst, int ldDst, int kOff) {
  __shared__ float tbuf[32][33];
  int n0 = blockIdx.x * 32, k0 = blockIdx.y * 32;
  int tx = threadIdx.x, ty = threadIdx.y;  // 32 x 8
#pragma unroll
  for (int i = 0; i < 32; i += 8) {
    int k = k0 + ty + i, n = n0 + tx;
    tbuf[ty + i][tx] = (k < Ks && n < Ns) ? src[(size_t)k * Ns + n] : 0.f;
  }
  __syncthreads();
#pragma unroll
  for (int i = 0; i < 32; i += 8) {
    int n = n0 + ty + i, k = k0 + tx;
    if (n < Ns && k < Ks) {
      int nd = PERM ? (((n & 511) << 2) | (n >> 9)) : n;
      dst[(size_t)nd * ldDst + kOff + k] = f2bf(tbuf[tx][ty + i]);
    }
  }
}

// fused: encbf (optional) + column mean, single pass over enc. grid (8, 64)
template <bool BF>
__global__ __launch_bounds__(256) void k_prep(const float* __restrict__ enc,
                                              short* __restrict__ encbf,
                                              float* __restrict__ mean_enc) {
  int b = blockIdx.y;
  int e = blockIdx.x * 256 + threadIdx.x;
  const float* p = enc + (size_t)b * NL * NE + e;
  short* q = encbf + (size_t)b * NL * NE + e;
  float s = 0.f;
  for (int l = 0; l < NL; ++l) {
    float v = p[(size_t)l * NE];
    s += v;
    if (BF) q[(size_t)l * NE] = f2bf(v);
  }
  mean_enc[(size_t)b * NE + e] = s * (1.f / NL);
}

__global__ void k_xemb(const int* __restrict__ caps, const float* __restrict__ emb,
                       short* __restrict__ xemb) {
  int i = blockIdx.x * 256 + threadIdx.x;
  int m = i & (NM - 1), b = (i >> 9) & (NB - 1), t = i >> 15;
  xemb[i] = f2bf(emb[(size_t)caps[b * NT + t] * NM + m]);
}

// h0/c0 partials: 16-way K-split. grid (256, 16)
__global__ void k_init0(const float* __restrict__ mean_enc, const float* __restrict__ W_h0,
                        const float* __restrict__ W_c0, float* __restrict__ PP) {
  int idx = blockIdx.x * 256 + threadIdx.x;  // b*1024 + half*512 + j
  int ks = blockIdx.y;
  int b = idx >> 10, jh = idx & 1023, half = jh >> 9, j = jh & 511;
  const float* W = half ? W_c0 : W_h0;
  const float* mp = mean_enc + (size_t)b * NE + ks * 128;
  const float* Wp = W + (size_t)(ks * 128) * ND + j;
  float acc = 0.f;
#pragma unroll 4
  for (int k = 0; k < 128; ++k) acc = fmaf(mp[k], Wp[(size_t)k * ND], acc);
  PP[(size_t)ks * 65536 + idx] = acc;
}

__global__ void k_init1(const float* __restrict__ PP, const float* __restrict__ b_h0,
                        const float* __restrict__ b_c0, float* __restrict__ c0,
                        short* __restrict__ hb0) {
  int idx = blockIdx.x * 256 + threadIdx.x;  // b*512 + j
  int b = idx >> 9, j = idx & 511;
  float ah = b_h0[j], ac = b_c0[j];
  for (int s = 0; s < 16; ++s) {
    const float* p = PP + (size_t)s * 65536 + b * 1024;
    ah += p[j]; ac += p[512 + j];
  }
  c0[idx] = tanhf(ac);
  hb0[idx] = f2bf(tanhf(ah));
}

// e_proj = enc @ W_enc + b_enc (bf16 out). 128x128 tile, 1D grid 392, XCD-chunked
template <bool BF>
__global__ __launch_bounds__(256) void k_eproj(const float* __restrict__ enc,
                                               const short* __restrict__ encbf,
                                               const short* __restrict__ We_t,
                                               const float* __restrict__ b_enc,
                                               short* __restrict__ e_proj) {
  constexpr int FM = 4, FN = 4;  // 128 x 128
  __shared__ short ldsA[128 * 64], ldsB[128 * 64];
  int p = blockIdx.x;
  int l = (p & 7) * 49 + (p >> 3);       // 392 = 8*49, contiguous per XCD
  int bn = (l & 3) * 128, bm = (l >> 2) * 128;
  int tid = threadIdx.x, lane = tid & 63, wave = tid >> 6, wr = wave >> 1, wc = wave & 1;
  f32x4 acc[FM][FN];
#pragma unroll
  for (int m = 0; m < FM; ++m)
#pragma unroll
    for (int n = 0; n < FN; ++n) acc[m][n] = (f32x4){0.f, 0.f, 0.f, 0.f};
  for (int k0 = 0; k0 < NE; k0 += 64) {
    __syncthreads();
    if (BF) stage_direct<128>(encbf + (size_t)bm * NE + k0, NE, 127, ldsA, tid);
    else    stage_f32cvt<128>(enc + (size_t)bm * NE + k0, NE, ldsA, tid);
    stage_direct<128>(We_t + (size_t)bn * NE + k0, NE, 127, ldsB, tid);
    __syncthreads();
    mma_tiles<FM, FN>(ldsA, ldsB, wr, wc, lane, acc);
  }
#pragma unroll
  for (int m = 0; m < FM; ++m)
#pragma unroll
    for (int n = 0; n < FN; ++n) {
      int col = bn + wc * FN * 16 + n * 16 + (lane & 15);
      float bias = b_enc[col];
#pragma unroll
      for (int r = 0; r < 4; ++r) {
        int row = bm + wr * FM * 16 + m * 16 + (lane >> 4) * 4 + r;
        e_proj[(size_t)row * NA + col] = f2bf(acc[m][n][r] + bias);
      }
    }
}

// fused h-GEMM: h_bf [64,512] @ Wall_t^T -> d | gate | hWhh' | preds(t). 64x64 tile
__global__ __launch_bounds__(256) void k_hgemm(const short* __restrict__ h_bf,
                                               const short* __restrict__ Wall_t,
                                               const float* __restrict__ b_dec,
                                               const float* __restrict__ b_beta,
                                               const float* __restrict__ b_fc,
                                               const int* __restrict__ clen,
                                               float* __restrict__ d_buf,
                                               float* __restrict__ gatebuf,
                                               float* __restrict__ hWhh,
                                               float* __restrict__ preds, int t) {
  constexpr int FM = 2, FN = 2;  // 64 x 64, 4 waves
  __shared__ short ldsA[64 * 64], ldsB[64 * 64];
  int bn = blockIdx.x * 64;
  int tid = threadIdx.x, lane = tid & 63, wave = tid >> 6, wr = wave >> 1, wc = wave & 1;
  int rowClampB = NALL2 - 1 - bn; if (rowClampB > 63) rowClampB = 63;
  f32x4 acc[FM][FN];
#pragma unroll
  for (int m = 0; m < FM; ++m)
#pragma unroll
    for (int n = 0; n < FN; ++n) acc[m][n] = (f32x4){0.f, 0.f, 0.f, 0.f};
  for (int k0 = 0; k0 < ND; k0 += 64) {
    __syncthreads();
    stage_direct<64>(h_bf + k0, ND, 63, ldsA, tid);
    stage_direct<64>(Wall_t + (size_t)bn * ND + k0, ND, rowClampB, ldsB, tid);
    __syncthreads();
    mma_tiles<FM, FN>(ldsA, ldsB, wr, wc, lane, acc);
  }
#pragma unroll
  for (int m = 0; m < FM; ++m)
#pragma unroll
    for (int r = 0; r < 4; ++r) {
      int row = wr * FM * 16 + m * 16 + (lane >> 4) * 4 + r;  // batch
      float mf = ((clen[row] - 1) > t) ? 1.f : 0.f;
#pragma unroll
      for (int n = 0; n < FN; ++n) {
        int col = bn + wc * FN * 16 + n * 16 + (lane & 15);
        float a = acc[m][n][r];
        if (bn < OFF_GATE) {
          d_buf[(size_t)row * NA + col] = a + b_dec[col];
        } else if (bn < OFF_HWHH2) {
          int e = col - OFF_GATE;
          gatebuf[(size_t)row * NE + e] = sigmoidf_(a + b_beta[e]);
        } else if (bn < OFF_PRED2) {
          hWhh[(size_t)row * NG + (col - OFF_HWHH2)] = a;
        } else {
          int v = col - OFF_PRED2;
          if (v < NV) preds[((size_t)row * NML + t) * NV + v] = mf * (a + b_fc[v]);
        }
      }
    }
}

// ---------- per-step kernels ----------

__global__ __launch_bounds__(256) void k_energy(const short* __restrict__ e_proj,
                                                const float* __restrict__ d_buf,
                                                const float* __restrict__ w_att,
                                                const float* __restrict__ b_att,
                                                float* __restrict__ energy) {
  int tid = threadIdx.x, wave = tid >> 6, lane = tid & 63;
  int row = blockIdx.x * 4 + wave;  // b*196 + l
  int b = row / NL;
  short8v ev = *(const short8v*)(e_proj + (size_t)row * NA + lane * 8);
  const float* dp = d_buf + (size_t)b * NA + lane * 8;
  float4 d0 = *(const float4*)dp, d1 = *(const float4*)(dp + 4);
  const float* wp = w_att + lane * 8;
  float4 w0 = *(const float4*)wp, w1 = *(const float4*)(wp + 4);
  float dd[8] = {d0.x, d0.y, d0.z, d0.w, d1.x, d1.y, d1.z, d1.w};
  float ww[8] = {w0.x, w0.y, w0.z, w0.w, w1.x, w1.y, w1.z, w1.w};
  float acc = 0.f;
#pragma unroll
  for (int i = 0; i < 8; ++i) {
    float v = bf2f(ev[i]) + dd[i];
    acc = fmaf(fmaxf(v, 0.f), ww[i], acc);
  }
#pragma unroll
  for (int off = 32; off; off >>= 1) acc += __shfl_down(acc, off);
  if (lane == 0) energy[row] = acc + b_att[0];
}

// softmax (per-block recompute) + ctx + gate -> gctx bf16. grid (4, 64)
template <bool BF>
__global__ __launch_bounds__(256) void k_ctx(const short* __restrict__ encbf,
                                             const float* __restrict__ encf,
                                             const float* __restrict__ energy,
                                             const float* __restrict__ gatebuf,
                                             const int* __restrict__ clen,
                                             short* __restrict__ gctx,
                                             float* __restrict__ alphas_out, int t) {
  int b = blockIdx.y, e0 = blockIdx.x * 512, tid = threadIdx.x;
  __shared__ float al[NL];
  __shared__ float red[8];
  int wave = tid >> 6, lane = tid & 63;
  float v = (tid < NL) ? energy[b * NL + tid] : -INFINITY;
  float mx = v;
#pragma unroll
  for (int off = 32; off; off >>= 1) mx = fmaxf(mx, __shfl_down(mx, off));
  if (lane == 0) red[wave] = mx;
  __syncthreads();
  if (tid == 0) red[0] = fmaxf(fmaxf(red[0], red[1]), fmaxf(red[2], red[3]));
  __syncthreads();
  mx = red[0];
  float ex = (tid < NL) ? expf(v - mx) : 0.f;
  float sm = ex;
#pragma unroll
  for (int off = 32; off; off >>= 1) sm += __shfl_down(sm, off);
  if (lane == 0) red[4 + wave] = sm;
  __syncthreads();
  if (tid == 0) red[0] = 1.f / (red[4] + red[5] + red[6] + red[7]);
  __syncthreads();
  float alv = ex * red[0];
  if (tid < NL) {
    al[tid] = alv;
    if (blockIdx.x == 0) {
      float mf = ((clen[b] - 1) > t) ? 1.f : 0.f;
      alphas_out[((size_t)b * NML + t) * NL + tid] = alv * mf;
    }
  }
  __syncthreads();
  float cx0 = 0.f, cx1 = 0.f;
  if (BF) {
    const unsigned* p = (const unsigned*)(encbf + (size_t)b * NL * NE + e0) + tid;
#pragma unroll 4
    for (int l = 0; l < NL; ++l) {
      unsigned u = p[(size_t)l * (NE / 2)];
      cx0 = fmaf(al[l], bf2f((short)(u & 0xffffu)), cx0);
      cx1 = fmaf(al[l], bf2f((short)(u >> 16)), cx1);
    }
  } else {
    const float* p = encf + (size_t)b * NL * NE + e0 + 2 * tid;
#pragma unroll 4
    for (int l = 0; l < NL; ++l) {
      float2 u = *(const float2*)(p + (size_t)l * NE);
      cx0 = fmaf(al[l], u.x, cx0);
      cx1 = fmaf(al[l], u.y, cx1);
    }
  }
  int e = e0 + 2 * tid;
  const float* gp = gatebuf + (size_t)b * NE + e;
  unsigned out = (unsigned)(unsigned short)f2bf(cx0 * gp[0]) |
                 ((unsigned)(unsigned short)f2bf(cx1 * gp[1]) << 16);
  *(unsigned*)(gctx + (size_t)b * NE + e) = out;
}

// gates GEMM [emb|gctx] @ Wihx_t^T (col-interleaved) -> P[ks][64][2048]. grid (32, 8)
__global__ __launch_bounds__(256) void k_gates(const short* __restrict__ xemb_t,
                                               const short* __restrict__ gctx,
                                               const short* __restrict__ Wihx_t,
                                               float* __restrict__ P) {
  constexpr int FM = 2, FN = 2;  // 64 x 64
  __shared__ short ldsA[64 * 64], ldsB[64 * 64];
  int bn = blockIdx.x * 64, ks = blockIdx.y;
  int tid = threadIdx.x, lane = tid & 63, wave = tid >> 6, wr = wave >> 1, wc = wave & 1;
  f32x4 acc[FM][FN];
#pragma unroll
  for (int m = 0; m < FM; ++m)
#pragma unroll
    for (int n = 0; n < FN; ++n) acc[m][n] = (f32x4){0.f, 0.f, 0.f, 0.f};
  int kend = (ks + 1) * KSL;
  for (int k0 = ks * KSL; k0 < kend; k0 += 64) {
    const short* asrc; int aldk;
    if (k0 < NM) { asrc = xemb_t + k0;      aldk = NM; }
    else         { asrc = gctx + (k0 - NM); aldk = NE; }
    __syncthreads();
    stage_direct<64>(asrc, aldk, 63, ldsA, tid);
    stage_direct<64>(Wihx_t + (size_t)bn * KXG + k0, KXG, 63, ldsB, tid);
    __syncthreads();
    mma_tiles<FM, FN>(ldsA, ldsB, wr, wc, lane, acc);
  }
#pragma unroll
  for (int m = 0; m < FM; ++m)
#pragma unroll
    for (int n = 0; n < FN; ++n) {
      int col = bn + wc * FN * 16 + n * 16 + (lane & 15);
#pragma unroll
      for (int r = 0; r < 4; ++r) {
        int row = wr * FM * 16 + m * 16 + (lane >> 4) * 4 + r;
        P[((size_t)ks * NB + row) * NG + col] = acc[m][n][r];
      }
    }
}

// reduce partials + hWhh' (col-interleaved float4 = {i,f,g,o}), LSTM pointwise
__global__ void k_lstm(const float* __restrict__ P, const float* __restrict__ hWhh,
                       const float* __restrict__ b_ih, const float* __restrict__ b_hh,
                       const float* __restrict__ c_prev, float* __restrict__ c_next,
                       short* __restrict__ h_next) {
  int idx = blockIdx.x * 256 + threadIdx.x;  // b*512 + j
  int b = idx >> 9, j = idx & (ND - 1);
  float4 hw = *(const float4*)&hWhh[(size_t)b * NG + j * 4];
  float gi = b_ih[j] + b_hh[j] + hw.x;
  float gf = b_ih[j + ND] + b_hh[j + ND] + hw.y;
  float gg = b_ih[j + 2 * ND] + b_hh[j + 2 * ND] + hw.z;
  float go = b_ih[j + 3 * ND] + b_hh[j + 3 * ND] + hw.w;
#pragma unroll
  for (int s = 0; s < KSPL; ++s) {
    float4 v = *(const float4*)&P[((size_t)s * NB + b) * NG + j * 4];
    gi += v.x; gf += v.y; gg += v.z; go += v.w;
  }
  float cn = sigmoidf_(gf) * c_prev[idx] + sigmoidf_(gi) * tanhf(gg);
  float hn = sigmoidf_(go) * tanhf(cn);
  c_next[idx] = cn;
  h_next[idx] = f2bf(hn);
}

}  // namespace

extern "C" void kernel_launch(void* const* d_in, const int* in_sizes, int n_in,
                              void* d_out, int out_size, void* d_ws, size_t ws_size,
                              hipStream_t stream) {
  (void)in_sizes; (void)n_in; (void)out_size;
  const float* enc    = (const float*)d_in[0];
  const int*   caps   = (const int*)d_in[1];
  const int*   clen   = (const int*)d_in[2];
  const float* W_enc  = (const float*)d_in[3];
  const float* b_enc  = (const float*)d_in[4];
  const float* W_dec  = (const float*)d_in[5];
  const float* b_dec  = (const float*)d_in[6];
  const float* w_att  = (const float*)d_in[7];
  const float* b_att  = (const float*)d_in[8];
  const float* emb    = (const float*)d_in[9];
  const float* W_ih   = (const float*)d_in[10];
  const float* b_ih   = (const float*)d_in[11];
  const float* W_hh   = (const float*)d_in[12];
  const float* b_hh   = (const float*)d_in[13];
  const float* W_h0   = (const float*)d_in[14];
  const float* b_h0   = (const float*)d_in[15];
  const float* W_c0   = (const float*)d_in[16];
  const float* b_c0   = (const float*)d_in[17];
  const float* W_beta = (const float*)d_in[18];
  const float* b_beta = (const float*)d_in[19];
  const float* W_fc   = (const float*)d_in[20];
  const float* b_fc   = (const float*)d_in[21];

  float* ws     = (float*)d_ws;
  float* preds  = (float*)d_out;                   // [B][ML][V]
  float* alphas = preds + (size_t)NB * NML * NV;   // [B][ML][L]

  float* mean_enc = ws + WS_MEAN;
  float* cbuf[2]  = {ws + WS_C0, ws + WS_C1};
  float* d_buf    = ws + WS_D;
  float* gatebuf  = ws + WS_GATE;
  float* hWhh     = ws + WS_HWHH;
  float* energy   = ws + WS_EN;
  float* PP       = ws + WS_PP;
  short* shb      = (short*)(ws + WS_SHB);
  short* hbuf[2]  = {shb + SH_HB0, shb + SH_HB1};
  short* xemb     = shb + SH_XEMB;
  short* gctx     = shb + SH_GCTX;
  short* e_proj   = shb + SH_EPROJ;
  short* We_t     = shb + SH_WET;
  short* Wihx_t   = shb + SH_WIHX;
  short* Wall_t   = shb + SH_WALL;
  short* encbf    = shb + SH_ENCBF;
  const bool use_bf = ws_size >= BYTES_ENC;

  // one-time weight transposes (dst[n][k] bf16)
  k_tcvt<false><<<dim3(NA / 32, NE / 32), dim3(32, 8), 0, stream>>>(W_enc, NE, NA, We_t, NE, 0);
  k_tcvt<true><<<dim3(NG / 32, KXG / 32), dim3(32, 8), 0, stream>>>(
      W_ih, KXG, NG, Wihx_t, KXG, 0);
  k_tcvt<false><<<dim3(NA / 32, ND / 32), dim3(32, 8), 0, stream>>>(W_dec, ND, NA, Wall_t, ND, 0);
  k_tcvt<false><<<dim3(NE / 32, ND / 32), dim3(32, 8), 0, stream>>>(
      W_beta, ND, NE, Wall_t + (size_t)OFF_GATE * ND, ND, 0);
  k_tcvt<true><<<dim3(NG / 32, ND / 32), dim3(32, 8), 0, stream>>>(
      W_hh, ND, NG, Wall_t + (size_t)OFF_HWHH2 * ND, ND, 0);
  k_tcvt<false><<<dim3((NV + 31) / 32, ND / 32), dim3(32, 8), 0, stream>>>(
      W_fc, ND, NV, Wall_t + (size_t)OFF_PRED2 * ND, ND, 0);
  if (use_bf)
    k_prep<true><<<dim3(NE / 256, NB), 256, 0, stream>>>(enc, encbf, mean_enc);
  else
    k_prep<false><<<dim3(NE / 256, NB), 256, 0, stream>>>(enc, encbf, mean_enc);
  k_xemb<<<(NML * NB * NM) / 256, 256, 0, stream>>>(caps, emb, xemb);

  k_init0<<<dim3(256, 16), 256, 0, stream>>>(mean_enc, W_h0, W_c0, PP);
  k_init1<<<(NB * ND) / 256, 256, 0, stream>>>(PP, b_h0, b_c0, cbuf[0], hbuf[0]);
  if (use_bf)
    k_eproj<true><<<392, 256, 0, stream>>>(enc, encbf, We_t, b_enc, e_proj);
  else
    k_eproj<false><<<392, 256, 0, stream>>>(enc, encbf, We_t, b_enc, e_proj);
  // h0-dependent d / gate / hWhh only (first 72 column-tiles)
  k_hgemm<<<OFF_PRED2 / 64, 256, 0, stream>>>(hbuf[0], Wall_t, b_dec, b_beta, b_fc, clen,
                                              d_buf, gatebuf, hWhh, preds, 0);

  for (int t = 0; t < NML; ++t) {
    short* h_prev = hbuf[t & 1];
    short* h_next = hbuf[1 - (t & 1)];
    float* c_prev = cbuf[t & 1];
    float* c_next = cbuf[1 - (t & 1)];
    k_energy<<<(NB * NL) / 4, 256, 0, stream>>>(e_proj, d_buf, w_att, b_att, energy);
    if (use_bf)
      k_ctx<true><<<dim3(NE / 512, NB), 256, 0, stream>>>(encbf, enc, energy, gatebuf,
                                                          clen, gctx, alphas, t);
    else
      k_ctx<false><<<dim3(NE / 512, NB), 256, 0, stream>>>(encbf, enc, energy, gatebuf,
                                                           clen, gctx, alphas, t);
    k_gates<<<dim3(NG / 64, KSPL), 256, 0, stream>>>(xemb + (size_t)t * NB * NM, gctx,
                                                     Wihx_t, PP);
    k_lstm<<<(NB * ND) / 256, 256, 0, stream>>>(PP, hWhh, b_ih, b_hh, c_prev, c_next,
                                                h_next);
    (void)h_prev;
    // preds(t) + d/gate/hWhh for step t+1
    k_hgemm<<<(NALL2 + 63) / 64, 256, 0, stream>>>(h_next, Wall_t, b_dec, b_beta, b_fc,
                                                   clen, d_buf, gatebuf, hWhh, preds, t);
  }
}

// Round 11
// 1156.200 us; speedup vs baseline: 1.4313x; 1.0012x over previous
//
#include <hip/hip_runtime.h>
#include <math.h>

namespace {

constexpr int NB  = 64;     // batch
constexpr int NL  = 196;    // L
constexpr int NE  = 2048;   // E
constexpr int ND  = 512;    // D
constexpr int NA  = 512;    // A
constexpr int NM  = 512;    // M
constexpr int NV  = 30000;  // vocab
constexpr int NT  = 21;     // T
constexpr int NML = 20;     // max_len
constexpr int NG  = 4 * ND;                 // 2048 (gates, col-interleaved j*4+g)
constexpr int KXG = NM + NE;                // 2560 (gates K: [emb | gctx])
constexpr int KSPL = 8, KSL = KXG / KSPL;   // 320
// per-step h-GEMM N-space: [d (512) | gate (2048) | hWhh' (2048)]
constexpr int NDG = ND + NE + NG;           // 4608
constexpr int OFF_GATE = ND;                // 512
constexpr int OFF_HWHH = ND + NE;           // 2560

// ---- workspace layout (float elements) ----
constexpr size_t WS_MEAN = 0;                                  // [64][2048]
constexpr size_t WS_C0   = WS_MEAN + (size_t)NB * NE;
constexpr size_t WS_C1   = WS_C0   + (size_t)NB * ND;
constexpr size_t WS_D    = WS_C1   + (size_t)NB * ND;          // [64][512]
constexpr size_t WS_GATE = WS_D    + (size_t)NB * NA;          // [64][2048]
constexpr size_t WS_HWHH = WS_GATE + (size_t)NB * NE;          // [64][2048] interleaved
constexpr size_t WS_EN   = WS_HWHH + (size_t)NB * NG;          // [64][196]
constexpr size_t WS_PP   = WS_EN   + (size_t)NB * NL;          // 1048576
constexpr size_t WS_SHB  = WS_PP   + (size_t)1048576;
// (short elements from shb)
constexpr size_t SH_HALL = 0;                                  // [21][64][512]
constexpr size_t SH_XEMB = SH_HALL + (size_t)(NML + 1) * NB * ND;  // [20][64][512]
constexpr size_t SH_GCTX = SH_XEMB + (size_t)NML * NB * NM;    // [64][2048]
constexpr size_t SH_EPROJ= SH_GCTX + (size_t)NB * NE;          // [12544][512]
constexpr size_t SH_WET  = SH_EPROJ+ (size_t)NB * NL * NA;     // [512][2048]
constexpr size_t SH_WIHX = SH_WET  + (size_t)NA * NE;          // [2048][2560]
constexpr size_t SH_WALL = SH_WIHX + (size_t)NG * KXG;         // [4608][512]
constexpr size_t SH_WFC  = SH_WALL + (size_t)NDG * ND;         // [30000][512]
constexpr size_t SH_ENCBF= SH_WFC  + (size_t)NV * ND;          // [64][196][2048] optional
constexpr size_t SH_END  = SH_ENCBF+ (size_t)NB * NL * NE;
constexpr size_t BYTES_ENC = WS_SHB * 4 + SH_END * 2;

typedef __attribute__((ext_vector_type(8))) short short8v;
typedef __attribute__((ext_vector_type(4))) float f32x4;

__device__ __forceinline__ float sigmoidf_(float x) { return 1.f / (1.f + expf(-x)); }
__device__ __forceinline__ short f2bf(float f) {
  unsigned u = __float_as_uint(f);
  return (short)((u + 0x7FFFu + ((u >> 16) & 1u)) >> 16);
}
__device__ __forceinline__ float bf2f(short s) {
  return __uint_as_float(((unsigned)(unsigned short)s) << 16);
}

// ---------- MFMA building blocks ----------
// LDS tile: [row][64 k] bf16, 8 x 16B chunks/row, chunk for global kb at slot
// kb ^ (row&7). Staged via global_load_lds with PRE-SWIZZLED global source.

__device__ __forceinline__ void gload16(const short* g, short* l) {
  __builtin_amdgcn_global_load_lds(
      (const __attribute__((address_space(1))) unsigned int*)(g),
      (__attribute__((address_space(3))) unsigned int*)(l), 16, 0, 0);
}

template <int R>  // stage R rows x 64 k bf16 (R multiple of 8); 4 waves
__device__ __forceinline__ void stage_direct(const short* __restrict__ src, int ldK,
                                             int rowClamp, short* lds, int tid) {
  int wv = tid >> 6, lane = tid & 63;
  int sub = lane >> 3;
  int kb  = (lane & 7) ^ sub;
#pragma unroll
  for (int g = wv; g < R / 8; g += 4) {
    int row = g * 8 + sub;
    int r = row < rowClamp ? row : rowClamp;
    gload16(src + (size_t)r * ldK + (kb << 3), lds + g * 512);
  }
}

template <int R>  // reg-staged f32->bf16 fallback
__device__ __forceinline__ void stage_f32cvt(const float* __restrict__ src, int ldK,
                                             short* lds, int tid) {
#pragma unroll
  for (int cidx = tid; cidx < R * 8; cidx += 256) {
    int row = cidx >> 3, kb = cidx & 7;
    const float* p = src + (size_t)row * ldK + kb * 8;
    float4 x = *(const float4*)p;
    float4 y = *(const float4*)(p + 4);
    short8v s;
    s[0] = f2bf(x.x); s[1] = f2bf(x.y); s[2] = f2bf(x.z); s[3] = f2bf(x.w);
    s[4] = f2bf(y.x); s[5] = f2bf(y.y); s[6] = f2bf(y.z); s[7] = f2bf(y.w);
    *(short8v*)(lds + row * 64 + ((kb ^ (row & 7)) << 3)) = s;
  }
}

template <int FM, int FN>
__device__ __forceinline__ void mma_tiles(const short* ldsA, const short* ldsB,
                                          int wr, int wc, int lane, f32x4 acc[FM][FN]) {
  int l15 = lane & 15;
#pragma unroll
  for (int kk = 0; kk < 2; ++kk) {
    int kb0 = kk * 4 + (lane >> 4);
    short8v a[FM], b[FN];
#pragma unroll
    for (int m = 0; m < FM; ++m) {
      int row = wr * FM * 16 + m * 16 + l15;
      a[m] = *(const short8v*)(ldsA + row * 64 + ((kb0 ^ (row & 7)) << 3));
    }
#pragma unroll
    for (int n = 0; n < FN; ++n) {
      int row = wc * FN * 16 + n * 16 + l15;
      b[n] = *(const short8v*)(ldsB + row * 64 + ((kb0 ^ (row & 7)) << 3));
    }
#pragma unroll
    for (int m = 0; m < FM; ++m)
#pragma unroll
      for (int n = 0; n < FN; ++n)
        acc[m][n] = __builtin_amdgcn_mfma_f32_16x16x32_bf16(a[m], b[n], acc[m][n], 0, 0, 0);
  }
}

// ---------- one-time kernels ----------

// transpose+convert; PERM interleaves gate columns: n' = (n&511)*4 + (n>>9)
template <bool PERM>
__global__ __launch_bounds__(256) void k_tcvt(const float* __restrict__ src, int Ks, int Ns,
                                              short* __restrict__ dst, int ldDst, int kOff) {
  __shared__ float tbuf[32][33];
  int n0 = blockIdx.x * 32, k0 = blockIdx.y * 32;
  int tx = threadIdx.x, ty = threadIdx.y;  // 32 x 8
#pragma unroll
  for (int i = 0; i < 32; i += 8) {
    int k = k0 + ty + i, n = n0 + tx;
    tbuf[ty + i][tx] = (k < Ks && n < Ns) ? src[(size_t)k * Ns + n] : 0.f;
  }
  __syncthreads();
#pragma unroll
  for (int i = 0; i < 32; i += 8) {
    int n = n0 + ty + i, k = k0 + tx;
    if (n < Ns && k < Ks) {
      int nd = PERM ? (((n & 511) << 2) | (n >> 9)) : n;
      dst[(size_t)nd * ldDst + kOff + k] = f2bf(tbuf[tx][ty + i]);
    }
  }
}

// fused: encbf (optional) + column mean, single pass over enc. grid (8, 64)
template <bool BF>
__global__ __launch_bounds__(256) void k_prep(const float* __restrict__ enc,
                                              short* __restrict__ encbf,
                                              float* __restrict__ mean_enc) {
  int b = blockIdx.y;
  int e = blockIdx.x * 256 + threadIdx.x;
  const float* p = enc + (size_t)b * NL * NE + e;
  short* q = encbf + (size_t)b * NL * NE + e;
  float s = 0.f;
  for (int l = 0; l < NL; ++l) {
    float v = p[(size_t)l * NE];
    s += v;
    if (BF) q[(size_t)l * NE] = f2bf(v);
  }
  mean_enc[(size_t)b * NE + e] = s * (1.f / NL);
}

__global__ void k_xemb(const int* __restrict__ caps, const float* __restrict__ emb,
                       short* __restrict__ xemb) {
  int i = blockIdx.x * 256 + threadIdx.x;
  int m = i & (NM - 1), b = (i >> 9) & (NB - 1), t = i >> 15;
  xemb[i] = f2bf(emb[(size_t)caps[b * NT + t] * NM + m]);
}

// h0/c0 partials: 16-way K-split. grid (256, 16)
__global__ void k_init0(const float* __restrict__ mean_enc, const float* __restrict__ W_h0,
                        const float* __restrict__ W_c0, float* __restrict__ PP) {
  int idx = blockIdx.x * 256 + threadIdx.x;  // b*1024 + half*512 + j
  int ks = blockIdx.y;
  int b = idx >> 10, jh = idx & 1023, half = jh >> 9, j = jh & 511;
  const float* W = half ? W_c0 : W_h0;
  const float* mp = mean_enc + (size_t)b * NE + ks * 128;
  const float* Wp = W + (size_t)(ks * 128) * ND + j;
  float acc = 0.f;
#pragma unroll 4
  for (int k = 0; k < 128; ++k) acc = fmaf(mp[k], Wp[(size_t)k * ND], acc);
  PP[(size_t)ks * 65536 + idx] = acc;
}

__global__ void k_init1(const float* __restrict__ PP, const float* __restrict__ b_h0,
                        const float* __restrict__ b_c0, float* __restrict__ c0,
                        short* __restrict__ h0) {
  int idx = blockIdx.x * 256 + threadIdx.x;  // b*512 + j
  int b = idx >> 9, j = idx & 511;
  float ah = b_h0[j], ac = b_c0[j];
  for (int s = 0; s < 16; ++s) {
    const float* p = PP + (size_t)s * 65536 + b * 1024;
    ah += p[j]; ac += p[512 + j];
  }
  c0[idx] = tanhf(ac);
  h0[idx] = f2bf(tanhf(ah));
}

// e_proj = enc @ W_enc + b_enc (bf16 out). 128x128 tile, 1D grid 392, XCD-chunked
template <bool BF>
__global__ __launch_bounds__(256) void k_eproj(const float* __restrict__ enc,
                                               const short* __restrict__ encbf,
                                               const short* __restrict__ We_t,
                                               const float* __restrict__ b_enc,
                                               short* __restrict__ e_proj) {
  constexpr int FM = 4, FN = 4;
  __shared__ short ldsA[128 * 64], ldsB[128 * 64];
  int p = blockIdx.x;
  int l = (p & 7) * 49 + (p >> 3);       // 392 = 8*49, contiguous per XCD
  int bn = (l & 3) * 128, bm = (l >> 2) * 128;
  int tid = threadIdx.x, lane = tid & 63, wave = tid >> 6, wr = wave >> 1, wc = wave & 1;
  f32x4 acc[FM][FN];
#pragma unroll
  for (int m = 0; m < FM; ++m)
#pragma unroll
    for (int n = 0; n < FN; ++n) acc[m][n] = (f32x4){0.f, 0.f, 0.f, 0.f};
  for (int k0 = 0; k0 < NE; k0 += 64) {
    __syncthreads();
    if (BF) stage_direct<128>(encbf + (size_t)bm * NE + k0, NE, 127, ldsA, tid);
    else    stage_f32cvt<128>(enc + (size_t)bm * NE + k0, NE, ldsA, tid);
    stage_direct<128>(We_t + (size_t)bn * NE + k0, NE, 127, ldsB, tid);
    __syncthreads();
    mma_tiles<FM, FN>(ldsA, ldsB, wr, wc, lane, acc);
  }
#pragma unroll
  for (int m = 0; m < FM; ++m)
#pragma unroll
    for (int n = 0; n < FN; ++n) {
      int col = bn + wc * FN * 16 + n * 16 + (lane & 15);
      float bias = b_enc[col];
#pragma unroll
      for (int r = 0; r < 4; ++r) {
        int row = bm + wr * FM * 16 + m * 16 + (lane >> 4) * 4 + r;
        e_proj[(size_t)row * NA + col] = f2bf(acc[m][n][r] + bias);
      }
    }
}

// per-step h-GEMM: h [64,512] @ Wall_t^T -> d | gate | hWhh'. 64x64 tile, 72 blocks
__global__ __launch_bounds__(256) void k_hgemm_dg(const short* __restrict__ h_bf,
                                                  const short* __restrict__ Wall_t,
                                                  const float* __restrict__ b_dec,
                                                  const float* __restrict__ b_beta,
                                                  float* __restrict__ d_buf,
                                                  float* __restrict__ gatebuf,
                                                  float* __restrict__ hWhh) {
  constexpr int FM = 2, FN = 2;
  __shared__ short ldsA[64 * 64], ldsB[64 * 64];
  int bn = blockIdx.x * 64;
  int tid = threadIdx.x, lane = tid & 63, wave = tid >> 6, wr = wave >> 1, wc = wave & 1;
  f32x4 acc[FM][FN];
#pragma unroll
  for (int m = 0; m < FM; ++m)
#pragma unroll
    for (int n = 0; n < FN; ++n) acc[m][n] = (f32x4){0.f, 0.f, 0.f, 0.f};
  for (int k0 = 0; k0 < ND; k0 += 64) {
    __syncthreads();
    stage_direct<64>(h_bf + k0, ND, 63, ldsA, tid);
    stage_direct<64>(Wall_t + (size_t)bn * ND + k0, ND, 63, ldsB, tid);
    __syncthreads();
    mma_tiles<FM, FN>(ldsA, ldsB, wr, wc, lane, acc);
  }
#pragma unroll
  for (int m = 0; m < FM; ++m)
#pragma unroll
    for (int r = 0; r < 4; ++r) {
      int row = wr * FM * 16 + m * 16 + (lane >> 4) * 4 + r;  // batch
#pragma unroll
      for (int n = 0; n < FN; ++n) {
        int col = bn + wc * FN * 16 + n * 16 + (lane & 15);
        float a = acc[m][n][r];
        if (bn < OFF_GATE) {
          d_buf[(size_t)row * NA + col] = a + b_dec[col];
        } else if (bn < OFF_HWHH) {
          int e = col - OFF_GATE;
          gatebuf[(size_t)row * NE + e] = sigmoidf_(a + b_beta[e]);
        } else {
          hWhh[(size_t)row * NG + (col - OFF_HWHH)] = a;
        }
      }
    }
}

// ---------- per-step kernels ----------

__global__ __launch_bounds__(256) void k_energy(const short* __restrict__ e_proj,
                                                const float* __restrict__ d_buf,
                                                const float* __restrict__ w_att,
                                                const float* __restrict__ b_att,
                                                float* __restrict__ energy) {
  int tid = threadIdx.x, wave = tid >> 6, lane = tid & 63;
  int row = blockIdx.x * 4 + wave;  // b*196 + l
  int b = row / NL;
  short8v ev = *(const short8v*)(e_proj + (size_t)row * NA + lane * 8);
  const float* dp = d_buf + (size_t)b * NA + lane * 8;
  float4 d0 = *(const float4*)dp, d1 = *(const float4*)(dp + 4);
  const float* wp = w_att + lane * 8;
  float4 w0 = *(const float4*)wp, w1 = *(const float4*)(wp + 4);
  float dd[8] = {d0.x, d0.y, d0.z, d0.w, d1.x, d1.y, d1.z, d1.w};
  float ww[8] = {w0.x, w0.y, w0.z, w0.w, w1.x, w1.y, w1.z, w1.w};
  float acc = 0.f;
#pragma unroll
  for (int i = 0; i < 8; ++i) {
    float v = bf2f(ev[i]) + dd[i];
    acc = fmaf(fmaxf(v, 0.f), ww[i], acc);
  }
#pragma unroll
  for (int off = 32; off; off >>= 1) acc += __shfl_down(acc, off);
  if (lane == 0) energy[row] = acc + b_att[0];
}

// softmax (per-block recompute) + ctx + gate -> gctx bf16. grid (4, 64)
template <bool BF>
__global__ __launch_bounds__(256) void k_ctx(const short* __restrict__ encbf,
                                             const float* __restrict__ encf,
                                             const float* __restrict__ energy,
                                             const float* __restrict__ gatebuf,
                                             const int* __restrict__ clen,
                                             short* __restrict__ gctx,
                                             float* __restrict__ alphas_out, int t) {
  int b = blockIdx.y, e0 = blockIdx.x * 512, tid = threadIdx.x;
  __shared__ float al[NL];
  __shared__ float red[8];
  int wave = tid >> 6, lane = tid & 63;
  float v = (tid < NL) ? energy[b * NL + tid] : -INFINITY;
  float mx = v;
#pragma unroll
  for (int off = 32; off; off >>= 1) mx = fmaxf(mx, __shfl_down(mx, off));
  if (lane == 0) red[wave] = mx;
  __syncthreads();
  if (tid == 0) red[0] = fmaxf(fmaxf(red[0], red[1]), fmaxf(red[2], red[3]));
  __syncthreads();
  mx = red[0];
  float ex = (tid < NL) ? expf(v - mx) : 0.f;
  float sm = ex;
#pragma unroll
  for (int off = 32; off; off >>= 1) sm += __shfl_down(sm, off);
  if (lane == 0) red[4 + wave] = sm;
  __syncthreads();
  if (tid == 0) red[0] = 1.f / (red[4] + red[5] + red[6] + red[7]);
  __syncthreads();
  float alv = ex * red[0];
  if (tid < NL) {
    al[tid] = alv;
    if (blockIdx.x == 0) {
      float mf = ((clen[b] - 1) > t) ? 1.f : 0.f;
      alphas_out[((size_t)b * NML + t) * NL + tid] = alv * mf;
    }
  }
  __syncthreads();
  float cx0 = 0.f, cx1 = 0.f;
  if (BF) {
    const unsigned* p = (const unsigned*)(encbf + (size_t)b * NL * NE + e0) + tid;
#pragma unroll 4
    for (int l = 0; l < NL; ++l) {
      unsigned u = p[(size_t)l * (NE / 2)];
      cx0 = fmaf(al[l], bf2f((short)(u & 0xffffu)), cx0);
      cx1 = fmaf(al[l], bf2f((short)(u >> 16)), cx1);
    }
  } else {
    const float* p = encf + (size_t)b * NL * NE + e0 + 2 * tid;
#pragma unroll 4
    for (int l = 0; l < NL; ++l) {
      float2 u = *(const float2*)(p + (size_t)l * NE);
      cx0 = fmaf(al[l], u.x, cx0);
      cx1 = fmaf(al[l], u.y, cx1);
    }
  }
  int e = e0 + 2 * tid;
  const float* gp = gatebuf + (size_t)b * NE + e;
  unsigned out = (unsigned)(unsigned short)f2bf(cx0 * gp[0]) |
                 ((unsigned)(unsigned short)f2bf(cx1 * gp[1]) << 16);
  *(unsigned*)(gctx + (size_t)b * NE + e) = out;
}

// gates GEMM [emb|gctx] @ Wihx_t^T (col-interleaved) -> P[ks][64][2048]. grid (32, 8)
__global__ __launch_bounds__(256) void k_gates(const short* __restrict__ xemb_t,
                                               const short* __restrict__ gctx,
                                               const short* __restrict__ Wihx_t,
                                               float* __restrict__ P) {
  constexpr int FM = 2, FN = 2;
  __shared__ short ldsA[64 * 64], ldsB[64 * 64];
  int bn = blockIdx.x * 64, ks = blockIdx.y;
  int tid = threadIdx.x, lane = tid & 63, wave = tid >> 6, wr = wave >> 1, wc = wave & 1;
  f32x4 acc[FM][FN];
#pragma unroll
  for (int m = 0; m < FM; ++m)
#pragma unroll
    for (int n = 0; n < FN; ++n) acc[m][n] = (f32x4){0.f, 0.f, 0.f, 0.f};
  int kend = (ks + 1) * KSL;
  for (int k0 = ks * KSL; k0 < kend; k0 += 64) {
    const short* asrc; int aldk;
    if (k0 < NM) { asrc = xemb_t + k0;      aldk = NM; }
    else         { asrc = gctx + (k0 - NM); aldk = NE; }
    __syncthreads();
    stage_direct<64>(asrc, aldk, 63, ldsA, tid);
    stage_direct<64>(Wihx_t + (size_t)bn * KXG + k0, KXG, 63, ldsB, tid);
    __syncthreads();
    mma_tiles<FM, FN>(ldsA, ldsB, wr, wc, lane, acc);
  }
#pragma unroll
  for (int m = 0; m < FM; ++m)
#pragma unroll
    for (int n = 0; n < FN; ++n) {
      int col = bn + wc * FN * 16 + n * 16 + (lane & 15);
#pragma unroll
      for (int r = 0; r < 4; ++r) {
        int row = wr * FM * 16 + m * 16 + (lane >> 4) * 4 + r;
        P[((size_t)ks * NB + row) * NG + col] = acc[m][n][r];
      }
    }
}

// reduce partials + hWhh' (col-interleaved float4 = {i,f,g,o}), LSTM pointwise,
// write c_next / h_next (bf16, into h_all slot t+1)
__global__ void k_lstm(const float* __restrict__ P, const float* __restrict__ hWhh,
                       const float* __restrict__ b_ih, const float* __restrict__ b_hh,
                       const float* __restrict__ c_prev, float* __restrict__ c_next,
                       short* __restrict__ h_next) {
  int idx = blockIdx.x * 256 + threadIdx.x;  // b*512 + j
  int b = idx >> 9, j = idx & (ND - 1);
  float4 hw = *(const float4*)&hWhh[(size_t)b * NG + j * 4];
  float gi = b_ih[j] + b_hh[j] + hw.x;
  float gf = b_ih[j + ND] + b_hh[j + ND] + hw.y;
  float gg = b_ih[j + 2 * ND] + b_hh[j + 2 * ND] + hw.z;
  float go = b_ih[j + 3 * ND] + b_hh[j + 3 * ND] + hw.w;
#pragma unroll
  for (int s = 0; s < KSPL; ++s) {
    float4 v = *(const float4*)&P[((size_t)s * NB + b) * NG + j * 4];
    gi += v.x; gf += v.y; gg += v.z; go += v.w;
  }
  float cn = sigmoidf_(gf) * c_prev[idx] + sigmoidf_(gi) * tanhf(gg);
  float hn = sigmoidf_(go) * tanhf(cn);
  c_next[idx] = cn;
  h_next[idx] = f2bf(hn);
}

// ---------- epilogue: batched pred GEMM ----------
// preds[b][t][v] = mask * (h_{t+1} . Wfc[:,v] + b_fc[v]);  A rows = t*64 + b
// M = 1280, N = 30000, K = 512. 128x128 tiles, grid 2350, XCD-bijective n-major.
// Corrected coalesced epilogue: acc -> LDS [64][129] f32, then each 32-lane
// half-wave writes ONE row's 512B contiguously (8 rows per sweep).
__global__ __launch_bounds__(256) void k_pred(const short* __restrict__ h_all1,
                                              const short* __restrict__ Wfc_t,
                                              const float* __restrict__ b_fc,
                                              const int* __restrict__ clen,
                                              float* __restrict__ preds) {
  constexpr int FM = 4, FN = 4;  // 128 x 128
  constexpr int NT_M = 10, NT_N = (NV + 127) / 128;  // 10 x 235 = 2350
  constexpr int TOT = NT_M * NT_N;
  __shared__ __align__(16) char smem[64 * 129 * 4];  // 33024 B >= 2x16KB staging
  short* ldsA = (short*)smem;
  short* ldsB = ldsA + 128 * 64;
  float* fl   = (float*)smem;                        // [64][129] f32 view
  int p = blockIdx.x;
  int q = TOT / 8, r8 = TOT % 8;
  int xcd = p & 7, i = p >> 3;
  int l = (xcd < r8 ? xcd * (q + 1) : r8 * (q + 1) + (xcd - r8) * q) + i;
  int bm = (l % NT_M) * 128, bn = (l / NT_M) * 128;
  int tid = threadIdx.x, lane = tid & 63, wave = tid >> 6, wr = wave >> 1, wc = wave & 1;
  int rowClampB = NV - 1 - bn; if (rowClampB > 127) rowClampB = 127;
  f32x4 acc[FM][FN];
#pragma unroll
  for (int m = 0; m < FM; ++m)
#pragma unroll
    for (int n = 0; n < FN; ++n) acc[m][n] = (f32x4){0.f, 0.f, 0.f, 0.f};
  for (int k0 = 0; k0 < ND; k0 += 64) {
    __syncthreads();
    stage_direct<128>(h_all1 + (size_t)bm * ND + k0, ND, 127, ldsA, tid);
    stage_direct<128>(Wfc_t + (size_t)bn * ND + k0, ND, rowClampB, ldsB, tid);
    __syncthreads();
    mma_tiles<FM, FN>(ldsA, ldsB, wr, wc, lane, acc);
  }
  __syncthreads();  // staging reads done; reuse LDS for transpose-store
#pragma unroll
  for (int h = 0; h < 2; ++h) {
    // waves with wr==h own the 64 rows of this half: dump acc to LDS
    if (wr == h) {
#pragma unroll
      for (int m = 0; m < FM; ++m)
#pragma unroll
        for (int n = 0; n < FN; ++n)
#pragma unroll
          for (int r = 0; r < 4; ++r) {
            int lr = m * 16 + (lane >> 4) * 4 + r;      // 0..63 local row
            int lc = wc * 64 + n * 16 + (lane & 15);    // 0..127 local col
            fl[lr * 129 + lc] = acc[m][n][r];
          }
    }
    __syncthreads();
    // coalesced writeback: thread -> (row = tid>>5, 16B chunk = tid&31)
    {
      int lrb = tid >> 5;     // 0..7 row within sweep
      int c16 = tid & 31;     // 16B chunk: cols c16*4..c16*4+3
      int colb = c16 * 4;
#pragma unroll
      for (int s = 0; s < 8; ++s) {
        int row = s * 8 + lrb;                 // 0..63 local
        int grow = bm + h * 64 + row;
        int tt = grow >> 6, bb = grow & 63;
        float mf = ((clen[bb] - 1) > tt) ? 1.f : 0.f;
        int col = bn + colb;
        if (col < NV) {                        // NV%4==0 -> col+3 < NV too
          float4 v = *(float4*)&fl[row * 129 + colb];
          float4 bv = *(const float4*)&b_fc[col];
          v.x = mf * (v.x + bv.x);
          v.y = mf * (v.y + bv.y);
          v.z = mf * (v.z + bv.z);
          v.w = mf * (v.w + bv.w);
          *(float4*)(preds + ((size_t)bb * NML + tt) * NV + col) = v;
        }
      }
    }
    __syncthreads();
  }
}

}  // namespace

extern "C" void kernel_launch(void* const* d_in, const int* in_sizes, int n_in,
                              void* d_out, int out_size, void* d_ws, size_t ws_size,
                              hipStream_t stream) {
  (void)in_sizes; (void)n_in; (void)out_size;
  const float* enc    = (const float*)d_in[0];
  const int*   caps   = (const int*)d_in[1];
  const int*   clen   = (const int*)d_in[2];
  const float* W_enc  = (const float*)d_in[3];
  const float* b_enc  = (const float*)d_in[4];
  const float* W_dec  = (const float*)d_in[5];
  const float* b_dec  = (const float*)d_in[6];
  const float* w_att  = (const float*)d_in[7];
  const float* b_att  = (const float*)d_in[8];
  const float* emb    = (const float*)d_in[9];
  const float* W_ih   = (const float*)d_in[10];
  const float* b_ih   = (const float*)d_in[11];
  const float* W_hh   = (const float*)d_in[12];
  const float* b_hh   = (const float*)d_in[13];
  const float* W_h0   = (const float*)d_in[14];
  const float* b_h0   = (const float*)d_in[15];
  const float* W_c0   = (const float*)d_in[16];
  const float* b_c0   = (const float*)d_in[17];
  const float* W_beta = (const float*)d_in[18];
  const float* b_beta = (const float*)d_in[19];
  const float* W_fc   = (const float*)d_in[20];
  const float* b_fc   = (const float*)d_in[21];

  float* ws     = (float*)d_ws;
  float* preds  = (float*)d_out;                   // [B][ML][V]
  float* alphas = preds + (size_t)NB * NML * NV;   // [B][ML][L]

  float* mean_enc = ws + WS_MEAN;
  float* cbuf[2]  = {ws + WS_C0, ws + WS_C1};
  float* d_buf    = ws + WS_D;
  float* gatebuf  = ws + WS_GATE;
  float* hWhh     = ws + WS_HWHH;
  float* energy   = ws + WS_EN;
  float* PP       = ws + WS_PP;
  short* shb      = (short*)(ws + WS_SHB);
  short* h_all    = shb + SH_HALL;                 // [21][64][512]
  short* xemb     = shb + SH_XEMB;
  short* gctx     = shb + SH_GCTX;
  short* e_proj   = shb + SH_EPROJ;
  short* We_t     = shb + SH_WET;
  short* Wihx_t   = shb + SH_WIHX;
  short* Wall_t   = shb + SH_WALL;
  short* Wfc_t    = shb + SH_WFC;
  short* encbf    = shb + SH_ENCBF;
  const bool use_bf = ws_size >= BYTES_ENC;

  // one-time weight transposes (dst[n][k] bf16)
  k_tcvt<false><<<dim3(NA / 32, NE / 32), dim3(32, 8), 0, stream>>>(W_enc, NE, NA, We_t, NE, 0);
  k_tcvt<true><<<dim3(NG / 32, KXG / 32), dim3(32, 8), 0, stream>>>(
      W_ih, KXG, NG, Wihx_t, KXG, 0);
  k_tcvt<false><<<dim3(NA / 32, ND / 32), dim3(32, 8), 0, stream>>>(W_dec, ND, NA, Wall_t, ND, 0);
  k_tcvt<false><<<dim3(NE / 32, ND / 32), dim3(32, 8), 0, stream>>>(
      W_beta, ND, NE, Wall_t + (size_t)OFF_GATE * ND, ND, 0);
  k_tcvt<true><<<dim3(NG / 32, ND / 32), dim3(32, 8), 0, stream>>>(
      W_hh, ND, NG, Wall_t + (size_t)OFF_HWHH * ND, ND, 0);
  k_tcvt<false><<<dim3((NV + 31) / 32, ND / 32), dim3(32, 8), 0, stream>>>(
      W_fc, ND, NV, Wfc_t, ND, 0);
  if (use_bf)
    k_prep<true><<<dim3(NE / 256, NB), 256, 0, stream>>>(enc, encbf, mean_enc);
  else
    k_prep<false><<<dim3(NE / 256, NB), 256, 0, stream>>>(enc, encbf, mean_enc);
  k_xemb<<<(NML * NB * NM) / 256, 256, 0, stream>>>(caps, emb, xemb);

  k_init0<<<dim3(256, 16), 256, 0, stream>>>(mean_enc, W_h0, W_c0, PP);
  k_init1<<<(NB * ND) / 256, 256, 0, stream>>>(PP, b_h0, b_c0, cbuf[0], h_all);
  if (use_bf)
    k_eproj<true><<<392, 256, 0, stream>>>(enc, encbf, We_t, b_enc, e_proj);
  else
    k_eproj<false><<<392, 256, 0, stream>>>(enc, encbf, We_t, b_enc, e_proj);
  // h0-dependent d / gate / hWhh'
  k_hgemm_dg<<<NDG / 64, 256, 0, stream>>>(h_all, Wall_t, b_dec, b_beta,
                                           d_buf, gatebuf, hWhh);

  for (int t = 0; t < NML; ++t) {
    short* h_next = h_all + (size_t)(t + 1) * NB * ND;
    float* c_prev = cbuf[t & 1];
    float* c_next = cbuf[1 - (t & 1)];
    k_energy<<<(NB * NL) / 4, 256, 0, stream>>>(e_proj, d_buf, w_att, b_att, energy);
    if (use_bf)
      k_ctx<true><<<dim3(NE / 512, NB), 256, 0, stream>>>(encbf, enc, energy, gatebuf,
                                                          clen, gctx, alphas, t);
    else
      k_ctx<false><<<dim3(NE / 512, NB), 256, 0, stream>>>(encbf, enc, energy, gatebuf,
                                                           clen, gctx, alphas, t);
    k_gates<<<dim3(NG / 64, KSPL), 256, 0, stream>>>(xemb + (size_t)t * NB * NM, gctx,
                                                     Wihx_t, PP);
    k_lstm<<<(NB * ND) / 256, 256, 0, stream>>>(PP, hWhh, b_ih, b_hh, c_prev, c_next,
                                                h_next);
    if (t + 1 < NML)  // d / gate / hWhh' for step t+1
      k_hgemm_dg<<<NDG / 64, 256, 0, stream>>>(h_next, Wall_t, b_dec, b_beta,
                                               d_buf, gatebuf, hWhh);
  }
  // batched pred GEMM: all 20 steps at once, W_fc read once
  k_pred<<<10 * ((NV + 127) / 128), 256, 0, stream>>>(h_all + (size_t)NB * ND, Wfc_t,
                                                      b_fc, clen, preds);
}